// Round 12
// baseline (3619.147 us; speedup 1.0000x reference)
//
#include <hip/hip_runtime.h>
#include <hip/hip_bf16.h>

#define B_ 128
#define T_ 1024
#define I_ 512
#define H_ 1024
#define O_ 512
#define NBLK 256

typedef __attribute__((ext_vector_type(8))) short bf16x8;
typedef __attribute__((ext_vector_type(4))) float f32x4;
typedef __attribute__((ext_vector_type(4))) unsigned u32x4;
typedef unsigned short u16;

#define SLAB 131072  // u16 elements per 256 KB h-buffer slab

__device__ __forceinline__ unsigned f2bf_u(float f) {
  union { float f; unsigned u; } v; v.f = f;
  return (v.u + 0x7fffu + ((v.u >> 16) & 1u)) >> 16;  // RNE bf16
}

__device__ __forceinline__ bf16x8 cvt8(const float* __restrict__ p) {
  union { bf16x8 v; unsigned u[4]; } r;
  const float4 f0 = *(const float4*)p;
  const float4 f1 = *(const float4*)(p + 4);
  r.u[0] = f2bf_u(f0.x) | (f2bf_u(f0.y) << 16);
  r.u[1] = f2bf_u(f0.z) | (f2bf_u(f0.w) << 16);
  r.u[2] = f2bf_u(f1.x) | (f2bf_u(f1.y) << 16);
  r.u[3] = f2bf_u(f1.z) | (f2bf_u(f1.w) << 16);
  return r.v;
}

__device__ __forceinline__ bf16x8 cvt8r(float4 f0, float4 f1) {
  union { bf16x8 v; unsigned u[4]; } r;
  r.u[0] = f2bf_u(f0.x) | (f2bf_u(f0.y) << 16);
  r.u[1] = f2bf_u(f0.z) | (f2bf_u(f0.w) << 16);
  r.u[2] = f2bf_u(f1.x) | (f2bf_u(f1.y) << 16);
  r.u[3] = f2bf_u(f1.z) | (f2bf_u(f1.w) << 16);
  return r.v;
}

// strip generation-tag sign bits -> valid bf16x8 fragment
__device__ __forceinline__ bf16x8 mk8v(u32x4 t) {
  union { u32x4 u; bf16x8 b; } v;
  v.u = t & 0x7fff7fffu;
  return v.b;
}

// plain 16B load: L1/L2 cached — the FAST exchange path (local-L2 served)
#define LDPL(dst, base, off)                                   \
  asm volatile("global_load_dwordx4 %0, %1, off offset:" #off  \
               : "=v"(dst) : "v"(base) : "memory")
// coherence-point 16B load — the GUARANTEED path (r4..r11-proven)
#define LDTS(dst, base, off)                                              \
  asm volatile("global_load_dwordx4 %0, %1, off offset:" #off " sc0 sc1" \
               : "=v"(dst) : "v"(base) : "memory")
// plain dword store (write-through L1 -> local L2)
#define STPL(addr, val)                                                \
  asm volatile("global_store_dword %0, %1, off" ::"v"(addr), "v"(val)  \
               : "memory")
// coherence-point dword store (shadow copy, guaranteed visibility)
#define STSC(addr, val)                                                        \
  asm volatile("global_store_dword %0, %1, off sc0 sc1" ::"v"(addr), "v"(val)  \
               : "memory")

#define MFMA __builtin_amdgcn_mfma_f32_16x16x32_bf16

// counted vmcnt wait + scheduler fence (rule #18); vmcnt retires oldest-first
// (m135) so vmcnt(1) with queue [8 polls, shadow-store] drains exactly the
// polls while the shadow-store ack stays in flight (never on critical path).
#define WAITV(N)                                            \
  do {                                                      \
    asm volatile("s_waitcnt vmcnt(" #N ")" ::: "memory");   \
    __builtin_amdgcn_sched_barrier(0);                      \
  } while (0)

#define ISSUE8(LD, pb)                                    \
  do {                                                    \
    const u16* _b4 = (pb) + 2048;                         \
    LD(t0, (pb), 0);    LD(t1, (pb), 1024);               \
    LD(t2, (pb), 2048); LD(t3, (pb), 3072);               \
    LD(t4, _b4, 0);     LD(t5, _b4, 1024);                \
    LD(t6, _b4, 2048);  LD(t7, _b4, 3072);                \
  } while (0)

#define TAGCHK(ok, tw)                                                 \
  do {                                                                 \
    u32x4 _m4 = (t0 ^ (tw)) | (t1 ^ (tw)) | (t2 ^ (tw)) | (t3 ^ (tw)) | \
                (t4 ^ (tw)) | (t5 ^ (tw)) | (t6 ^ (tw)) | (t7 ^ (tw)); \
    unsigned _mm = _m4.x | _m4.y | _m4.z | _m4.w;                      \
    ok = __all((_mm & 0x80008000u) == 0u);                             \
  } while (0)

// Persistent RNN. Grid = 256 blocks x 256 threads (4 waves), 1 block/CU.
// Group g = blockIdx&7 (16 batch rows): congruence class => same XCD under
// the round-robin mapping (r9 FETCH evidence). Slot s = blockIdx>>3 (32 cols).
// h exchange, per step t (producing h_{t+1}, consuming h_t):
//   fast  : plain store -> shared local L2 into fast[(t+1)%8]; consumer makes
//           ONE plain-load attempt of fast[t%8] (8-deep rotation => the L1
//           line from 8 steps ago is evicted; re-polling a hot L1 line is
//           useless and was r5/r10's livelock, so we never re-poll plain).
//   shadow: sc1 store (issued before any spin => guaranteed progress under
//           ANY XCD mapping) + sc1 retry loop, r8-proven.
// Tags: mod-3 pattern over the two (always-0 after relu) bf16 sign bits per
// dword; rotation depth 8 with period-3 tags => stale slots never alias.
__global__ __launch_bounds__(256, 1) void rnn_persist(
    const float* __restrict__ x, const float* __restrict__ Wih,
    const float* __restrict__ bih, const float* __restrict__ Whh,
    const float* __restrict__ bhh, const float* __restrict__ Who,
    const float* __restrict__ bho, u16* __restrict__ fastb,
    u16* __restrict__ shadb, float* __restrict__ out) {
  __shared__ u16 w_lds[192 * 32 * 8];  // 96 KB: [k-octet o][col c][8 bf16]
  __shared__ float red[2][256 * 9];    // 18 KB double-buffered reduce scratch
  __shared__ float bias_lds[32];

  const int tid = threadIdx.x;
  const int w = tid >> 6;
  const int lane = tid & 63;
  const int lr = lane & 15;
  const int kg = lane >> 4;
  const int g = (int)blockIdx.x & 7;   // congruence group (same XCD)
  const int s = (int)blockIdx.x >> 3;  // column slot 0..31
  const int r0 = g * 16;
  const int c0 = s * 32;

  // ---- stage W tile [32 cols x 1536 K] into LDS ----
  for (int e = tid; e < 192 * 32; e += 256) {
    int o = e >> 5, c = e & 31;
    int k = o * 8, gc = c0 + c;
    const float* src = (k < H_) ? (Whh + (size_t)gc * H_ + k)
                                : (Wih + (size_t)gc * I_ + (k - H_));
    *(bf16x8*)&w_lds[e * 8] = cvt8(src);
  }
  if (tid < 32) bias_lds[tid] = bih[c0 + tid] + bhh[c0 + tid];
  __syncthreads();

  // LDS fragment bases (u16 units)
  const u16* wb_h = &w_lds[(((w * 32 + kg) * 32) + lr) * 8];
  const u16* wb_x = &w_lds[(((128 + w * 16 + kg) * 32) + lr) * 8];

  // per-lane offset inside a producer tile: row lr, k-octet kg (u16 units)
  const int loff = lr * 32 + kg * 8;
  // this wave consumes producer tiles w*8 .. w*8+7 of its group
  const size_t twave = ((size_t)(g * 32 + w * 8)) * 512;
  // this block produces tile (g,s); thread tid owns dword tid of it
  const size_t towndw = ((size_t)(g * 32 + s)) * 256 + tid;

  // reduce/store thread mapping (r7..r11-verified)
  const int rr = tid >> 4;           // row 0..15
  const int cpair = (tid & 15) * 2;  // col pair 0,2,..,30
  const int lane_r = (rr >> 2) << 4;
  const int reg_r = rr & 3;

  const f32x4 zero4 = {0.f, 0.f, 0.f, 0.f};
  f32x4 acc0, acc1;
  u32x4 t0, t1, t2, t3, t4, t5, t6, t7;
  unsigned pkst = 0;  // this thread's tagged h-word, held for the shadow store
  int c3 = 0;         // t % 3

  // ---- prologue: x-part for t=0 into acc ----
  {
    const float* px = x + ((size_t)(r0 + lr) * T_) * I_ + w * 128 + kg * 8;
    acc0 = zero4;
    acc1 = zero4;
#pragma unroll
    for (int i = 0; i < 4; ++i) {
      bf16x8 a = cvt8(px + i * 32);
      acc0 = MFMA(a, *(const bf16x8*)(wb_x + i * 1024), acc0, 0, 0, 0);
      acc1 = MFMA(a, *(const bf16x8*)(wb_x + i * 1024 + 128), acc1, 0, 0, 0);
    }
  }

#define HS(i, tv)                                                          \
  acc0 = MFMA(mk8v(tv), *(const bf16x8*)(wb_h + (i)*1024), acc0, 0, 0, 0); \
  acc1 = MFMA(mk8v(tv), *(const bf16x8*)(wb_h + (i)*1024 + 128), acc1, 0, 0, 0);

  for (int t = 0; t < T_; ++t) {
    const int slot = t & 7;
    const int nslot = (t + 1) & 7;
    const int c3n = (c3 == 2) ? 0 : c3 + 1;
    const unsigned tw = (c3 == 0) ? 0u : ((c3 == 1) ? 0x00008000u : 0x80000000u);
    const unsigned sp = (c3n == 0) ? 0u : ((c3n == 1) ? 0x00008000u : 0x80000000u);
    u16* fastc = fastb + (size_t)slot * SLAB;
    u16* shadc = shadb + (size_t)slot * SLAB;
    u16* fastn = fastb + (size_t)nslot * SLAB;
    const bool havex = (t + 1 < T_);

    // ---- PHASE A: consume h_t ----
    if (t > 0) {
      // one fast attempt (plain, local-L2) with the shadow store of h_t
      // issued right behind it; vmcnt(1) drains exactly the 8 polls.
      const u16* pb = fastc + twave + loff;
      ISSUE8(LDPL, pb);
      STSC((unsigned*)shadc + towndw, pkst);
      WAITV(1);
      bool ok;
      TAGCHK(ok, tw);
      if (!ok) {
        // guaranteed path: sc1 loop on the shadow copy (store already issued
        // by every producer before any spin => monotone progress)
        const u16* sb = shadc + twave + loff;
        do {
          ISSUE8(LDTS, sb);
          WAITV(0);
          TAGCHK(ok, tw);
        } while (!ok);
      }
      HS(0, t0) HS(1, t1) HS(2, t2) HS(3, t3)
      HS(4, t4) HS(5, t5) HS(6, t6) HS(7, t7)
    }

    // ---- PHASE B: issue x loads for t+1 ----
    float4 xa0, xa1, xa2, xa3, xa4, xa5, xa6, xa7;
    const float* px =
        x + ((size_t)(r0 + lr) * T_ + (t + 1)) * I_ + w * 128 + kg * 8;
    if (havex) {
      xa0 = *(const float4*)(px);      xa1 = *(const float4*)(px + 4);
      xa2 = *(const float4*)(px + 32); xa3 = *(const float4*)(px + 36);
      xa4 = *(const float4*)(px + 64); xa5 = *(const float4*)(px + 68);
      xa6 = *(const float4*)(px + 96); xa7 = *(const float4*)(px + 100);
    }

    // ---- PHASE C/D: cross-wave K-reduce, bias+relu, pack+tag, plain store --
    float* redc = red[t & 1];
    *(f32x4*)&redc[(w * 64 + lane) * 9] = acc0;
    *(f32x4*)&redc[(w * 64 + lane) * 9 + 4] = acc1;
    __syncthreads();
    {
      const int c1 = cpair + 1;
      const int l0 = lane_r | (cpair & 15), f0 = (cpair >> 4) * 4;
      const int l1 = lane_r | (c1 & 15), f1 = (c1 >> 4) * 4;
      float v0 = 0.f, v1 = 0.f;
#pragma unroll
      for (int ww = 0; ww < 4; ++ww) {
        v0 += redc[(ww * 64 + l0) * 9 + f0 + reg_r];
        v1 += redc[(ww * 64 + l1) * 9 + f1 + reg_r];
      }
      v0 += bias_lds[cpair];
      v1 += bias_lds[c1];
      v0 = v0 > 0.f ? v0 : 0.f;
      v1 = v1 > 0.f ? v1 : 0.f;
      pkst = (f2bf_u(v0) | (f2bf_u(v1) << 16)) | sp;
      STPL((unsigned*)fastn + towndw, pkst);  // write-through -> local L2
    }

    // ---- PHASE E: x-part MFMAs for t+1 ----
    f32x4 xacc0 = zero4, xacc1 = zero4;
    if (havex) {
      bf16x8 a0 = cvt8r(xa0, xa1), a1 = cvt8r(xa2, xa3);
      bf16x8 a2 = cvt8r(xa4, xa5), a3 = cvt8r(xa6, xa7);
      xacc0 = MFMA(a0, *(const bf16x8*)(wb_x), xacc0, 0, 0, 0);
      xacc1 = MFMA(a0, *(const bf16x8*)(wb_x + 128), xacc1, 0, 0, 0);
      xacc0 = MFMA(a1, *(const bf16x8*)(wb_x + 1024), xacc0, 0, 0, 0);
      xacc1 = MFMA(a1, *(const bf16x8*)(wb_x + 1152), xacc1, 0, 0, 0);
      xacc0 = MFMA(a2, *(const bf16x8*)(wb_x + 2048), xacc0, 0, 0, 0);
      xacc1 = MFMA(a2, *(const bf16x8*)(wb_x + 2176), xacc1, 0, 0, 0);
      xacc0 = MFMA(a3, *(const bf16x8*)(wb_x + 3072), xacc0, 0, 0, 0);
      xacc1 = MFMA(a3, *(const bf16x8*)(wb_x + 3200), xacc1, 0, 0, 0);
    }
    acc0 = xacc0;
    acc1 = xacc1;
    c3 = c3n;
  }

  // ---- output GEMM: consume h_T (slot 0, tag pattern for 1024%3==1) ----
  {
    const unsigned tw = 0x00008000u;  // PAT[1024 % 3]
    u16* fastc = fastb;               // slot 1024 & 7 == 0
    u16* shadc = shadb;
    const u16* pb = fastc + twave + loff;
    ISSUE8(LDPL, pb);
    STSC((unsigned*)shadc + towndw, pkst);  // shadow store of h_T
    WAITV(1);
    bool ok;
    TAGCHK(ok, tw);
    if (!ok) {
      const u16* sb = shadc + twave + loff;
      do {
        ISSUE8(LDTS, sb);
        WAITV(0);
        TAGCHK(ok, tw);
      } while (!ok);
    }
    const int c0o = s * 16;
    f32x4 o0 = zero4;
    const float* pwo = Who + (size_t)(c0o + lr) * H_ + w * 256 + kg * 8;
    o0 = MFMA(mk8v(t0), cvt8(pwo + 0), o0, 0, 0, 0);
    o0 = MFMA(mk8v(t1), cvt8(pwo + 32), o0, 0, 0, 0);
    o0 = MFMA(mk8v(t2), cvt8(pwo + 64), o0, 0, 0, 0);
    o0 = MFMA(mk8v(t3), cvt8(pwo + 96), o0, 0, 0, 0);
    o0 = MFMA(mk8v(t4), cvt8(pwo + 128), o0, 0, 0, 0);
    o0 = MFMA(mk8v(t5), cvt8(pwo + 160), o0, 0, 0, 0);
    o0 = MFMA(mk8v(t6), cvt8(pwo + 192), o0, 0, 0, 0);
    o0 = MFMA(mk8v(t7), cvt8(pwo + 224), o0, 0, 0, 0);
    float* redc = red[0];
    *(f32x4*)&redc[(w * 64 + lane) * 9] = o0;
    __syncthreads();
    const int cc = tid & 15;
    const int l0 = lane_r | cc;
    float v = 0.f;
#pragma unroll
    for (int ww = 0; ww < 4; ++ww) v += redc[(ww * 64 + l0) * 9 + reg_r];
    v += bho[c0o + cc];
    out[(size_t)(r0 + rr) * O_ + c0o + cc] = v;
  }
}

extern "C" void kernel_launch(void* const* d_in, const int* in_sizes, int n_in,
                              void* d_out, int out_size, void* d_ws,
                              size_t ws_size, hipStream_t stream) {
  const float* x = (const float*)d_in[0];
  const float* Wih = (const float*)d_in[1];
  const float* bih = (const float*)d_in[2];
  const float* Whh = (const float*)d_in[3];
  const float* bhh = (const float*)d_in[4];
  const float* Who = (const float*)d_in[5];
  const float* bho = (const float*)d_in[6];
  float* outp = (float*)d_out;

  const size_t SB = (size_t)SLAB * 2;  // 256 KB per slab
  char* ws = (char*)d_ws;
  u16* fastb = (u16*)ws;               // 8 slabs = 2 MB (fast, L2-local)
  u16* shadb = (u16*)(ws + 8 * SB);    // 8 slabs = 2 MB (shadow, sc1)

  // slot 0 = h_0: zeros (tag pattern 0 => immediately valid).
  // slots 1..7: 0xFF (sign bits 11 => invalid under every pattern).
  hipMemsetAsync(ws, 0x00, SB, stream);
  hipMemsetAsync(ws + SB, 0xFF, 7 * SB, stream);
  hipMemsetAsync(ws + 8 * SB, 0x00, SB, stream);
  hipMemsetAsync(ws + 9 * SB, 0xFF, 7 * SB, stream);

  void* args[] = {(void*)&x,     (void*)&Wih,   (void*)&bih, (void*)&Whh,
                  (void*)&bhh,   (void*)&Who,   (void*)&bho, (void*)&fastb,
                  (void*)&shadb, (void*)&outp};
  hipLaunchCooperativeKernel((void*)rnn_persist, dim3(NBLK), dim3(256), args,
                             0, stream);
}